// Round 3
// baseline (378.147 us; speedup 1.0000x reference)
//
#include <hip/hip_runtime.h>
#include <hip/hip_fp16.h>

#define B_SZ 2048
#define T_SZ 2048
#define F_SZ 8
#define LOG2E 1.44269504088896340736f
#define PLANE_DW (B_SZ * T_SZ * 2)        // dwords per u-plane (uint2 per (b,t))
#define PLANE_BYTES ((size_t)B_SZ * T_SZ * 8)

// ---------------------------------------------------------------------------
// Record layout (workspace), SoA by hidden unit u (3 planes):
//   plane_u[(b*T + t)] = uint2{ pk(Az_u, Ar_u), pk(Xh_u, m) }   (fp16 pairs)
// where  Az_u = -log2e*(xw_z + bias_i_z + bias_r_z)
//        Ar_u = -log2e*(xw_r + bias_i_r + bias_r_r)
//        Xh_u = 2*log2e*(xw_h + bias_i_h)          (bias_r_h folded in scan)
//        m    = any(x[b,t,:] != 0) ? 1 : 0
// Consecutive t are contiguous per plane -> scan loads dwordx4 per 2 steps,
// pass1 stores dense 16B/lane (no partial-cacheline write amplification).
// Pre-scaling makes sigmoid/tanh pure v_exp_f32 (2^x) in the scan.
// ---------------------------------------------------------------------------

typedef __fp16 h2_t __attribute__((ext_vector_type(2)));

static __device__ __forceinline__ unsigned pk2(float a, float b) {
  h2_t v = __builtin_amdgcn_cvt_pkrtz(a, b);
  return __builtin_bit_cast(unsigned, v);
}

// quad_perm DPP broadcast/butterfly (all lanes active at call sites)
template <int CTRL>
static __device__ __forceinline__ float bcast(float v) {
  return __builtin_bit_cast(float,
      __builtin_amdgcn_mov_dpp(__builtin_bit_cast(int, v), CTRL, 0xF, 0xF, false));
}

// ---------------------------- Pass 1 ---------------------------------------
static __device__ __forceinline__ void do_step(const float xr[8],
                                               const float K[72],
                                               const float off[9],
                                               unsigned o[6]) {
  float A[9];
#pragma unroll
  for (int c = 0; c < 9; c++) {
    float acc = xr[0] * K[0 * 9 + c];
#pragma unroll
    for (int f = 1; f < 8; f++) acc = fmaf(xr[f], K[f * 9 + c], acc);
    float sc = (c < 6) ? -LOG2E : 2.0f * LOG2E;
    A[c] = fmaf(sc, acc, off[c]);
  }
  bool any = false;
#pragma unroll
  for (int f = 0; f < 8; f++) any = any || (xr[f] != 0.0f);
  float mf = any ? 1.0f : 0.0f;
  o[0] = pk2(A[0], A[3]); o[1] = pk2(A[6], mf);   // u=0
  o[2] = pk2(A[1], A[4]); o[3] = pk2(A[7], mf);   // u=1
  o[4] = pk2(A[2], A[5]); o[5] = pk2(A[8], mf);   // u=2
}

__global__ __launch_bounds__(256) void gru_pass1(
    const float* __restrict__ x, const float* __restrict__ kern,
    const float* __restrict__ bi, const float* __restrict__ br,
    unsigned* __restrict__ rec) {
  unsigned g = blockIdx.x * 256u + threadIdx.x;
  unsigned b = g >> 10;                 // lanes consecutive in t -> coalesced
  unsigned t = (g & 1023u) << 1;        // each thread does timesteps t, t+1

  float K[72];                          // uniform addresses -> s_load
#pragma unroll
  for (int i = 0; i < 72; i++) K[i] = kern[i];
  float off[9];
#pragma unroll
  for (int c = 0; c < 9; c++)
    off[c] = (c < 6) ? (-LOG2E * (bi[c] + br[c])) : (2.0f * LOG2E * bi[c]);

  // 64B full-cache-line read of x[b, t:t+2, :], contiguous across the wave
  const float4* xp = (const float4*)(x + ((size_t)b * T_SZ + t) * F_SZ);
  float4 a0 = xp[0], a1 = xp[1], a2 = xp[2], a3 = xp[3];
  float x0[8] = {a0.x, a0.y, a0.z, a0.w, a1.x, a1.y, a1.z, a1.w};
  float x1[8] = {a2.x, a2.y, a2.z, a2.w, a3.x, a3.y, a3.z, a3.w};

  unsigned r0[6], r1[6];
  do_step(x0, K, off, r0);
  do_step(x1, K, off, r1);

  // 3 dense plane stores: lane i writes 16B at +16B stride -> 1KB/instr
  size_t e = ((size_t)b * T_SZ + t) * 2;   // dword offset within a plane
  uint4 w0, w1, w2;
  w0.x = r0[0]; w0.y = r0[1]; w0.z = r1[0]; w0.w = r1[1];
  w1.x = r0[2]; w1.y = r0[3]; w1.z = r1[2]; w1.w = r1[3];
  w2.x = r0[4]; w2.y = r0[5]; w2.z = r1[4]; w2.w = r1[5];
  *(uint4*)(rec + 0 * (size_t)PLANE_DW + e) = w0;
  *(uint4*)(rec + 1 * (size_t)PLANE_DW + e) = w1;
  *(uint4*)(rec + 2 * (size_t)PLANE_DW + e) = w2;
}

// ---------------------------- Pass 2 (scan) --------------------------------
// 4 lanes per batch row: lane u in {0,1,2} owns hidden unit u; lane 3 reads a
// duplicate of u=2 (wl=0 so it contributes nothing to the quad dot).
// Double-buffered 16-step pipeline: 8 named uint4 per bank (2 steps each).

#define DECL8(P) uint4 P##0, P##1, P##2, P##3, P##4, P##5, P##6, P##7

#define LOAD8(P, q) \
  do { \
    const char* _q = (q); \
    P##0 = *(const uint4*)(_q + 0 * 16); \
    P##1 = *(const uint4*)(_q + 1 * 16); \
    P##2 = *(const uint4*)(_q + 2 * 16); \
    P##3 = *(const uint4*)(_q + 3 * 16); \
    P##4 = *(const uint4*)(_q + 4 * 16); \
    P##5 = *(const uint4*)(_q + 5 * 16); \
    P##6 = *(const uint4*)(_q + 6 * 16); \
    P##7 = *(const uint4*)(_q + 7 * 16); \
  } while (0)

// One GRU step. HA = half2(Az,Ar), HB = half2(Xh,m). J is compile-time.
// fp16 addends feed the first FMA of each chain directly (v_fma_mix).
#define STEP1(HA, HB, J, tb) \
  do { \
    float h0 = bcast<0x00>(h); \
    float h1 = bcast<0x55>(h); \
    float h2 = bcast<0xAA>(h); \
    float omh = 1.0f - h; \
    float tz = fmaf(h0, Rz0, __half2float((HA).x)); \
    tz = fmaf(h1, Rz1, tz); tz = fmaf(h2, Rz2, tz); \
    float tr = fmaf(h0, Rr0, __half2float((HA).y)); \
    tr = fmaf(h1, Rr1, tr); tr = fmaf(h2, Rr2, tr); \
    float hh = fmaf(h0, Rh0, Ch); hh = fmaf(h1, Rh1, hh); hh = fmaf(h2, Rh2, hh); \
    float z = __builtin_amdgcn_rcpf(1.0f + __builtin_amdgcn_exp2f(tz)); \
    float r = __builtin_amdgcn_rcpf(1.0f + __builtin_amdgcn_exp2f(tr)); \
    float arg = fmaf(r, hh, __half2float((HB).x)); \
    float qd = __builtin_amdgcn_rcpf(1.0f + __builtin_amdgcn_exp2f(arg)); \
    float t1 = fmaf(-2.0f, qd, omh);      /* = tanh - h */ \
    float s = fmaf(-z, t1, t1);           /* = (1-z)*(hc-h) */ \
    float hf = h + s; \
    float mf = __half2float((HB).y); \
    h = fmaf(mf, s, h); \
    float pp = hf * wl; \
    pp += bcast<0xB1>(pp); \
    pp += bcast<0x4E>(pp); \
    float ov = fmaf(mf, pp, dbv); \
    if (((J) & 3) == 0) o0 = ov; \
    else if (((J) & 3) == 1) o1 = ov; \
    else if (((J) & 3) == 2) o2 = ov; \
    else if (u == 0) { \
      float4 v; v.x = o0; v.y = o1; v.z = o2; v.w = ov; \
      *(float4*)(out + (size_t)b * T_SZ + (tb) + (J) - 3) = v; \
    } \
  } while (0)

#define STEP2(Q, K2, tb) \
  do { \
    __half2 ha = __builtin_bit_cast(__half2, (Q).x); \
    __half2 hb = __builtin_bit_cast(__half2, (Q).y); \
    STEP1(ha, hb, 2 * (K2), tb); \
    __half2 hc2 = __builtin_bit_cast(__half2, (Q).z); \
    __half2 hd = __builtin_bit_cast(__half2, (Q).w); \
    STEP1(hc2, hd, 2 * (K2) + 1, tb); \
  } while (0)

#define COMPUTE8(P, tb) \
  do { \
    STEP2(P##0, 0, tb); STEP2(P##1, 1, tb); STEP2(P##2, 2, tb); \
    STEP2(P##3, 3, tb); STEP2(P##4, 4, tb); STEP2(P##5, 5, tb); \
    STEP2(P##6, 6, tb); STEP2(P##7, 7, tb); \
  } while (0)

__global__ __launch_bounds__(64) void gru_scan(
    const char* __restrict__ rec, const float* __restrict__ rk,
    const float* __restrict__ br, const float* __restrict__ dw,
    const float* __restrict__ db, float* __restrict__ out) {
  unsigned tid = blockIdx.x * 64u + threadIdx.x;
  unsigned b = tid >> 2;
  unsigned u = tid & 3u;

  float Rz0 = 0, Rz1 = 0, Rz2 = 0, Rr0 = 0, Rr1 = 0, Rr2 = 0;
  float Rh0 = 0, Rh1 = 0, Rh2 = 0, Ch = 0, wl = 0;
  if (u < 3) {
    Rz0 = -LOG2E * rk[0 * 9 + u];
    Rz1 = -LOG2E * rk[1 * 9 + u];
    Rz2 = -LOG2E * rk[2 * 9 + u];
    Rr0 = -LOG2E * rk[0 * 9 + 3 + u];
    Rr1 = -LOG2E * rk[1 * 9 + 3 + u];
    Rr2 = -LOG2E * rk[2 * 9 + 3 + u];
    Rh0 = 2.0f * LOG2E * rk[0 * 9 + 6 + u];
    Rh1 = 2.0f * LOG2E * rk[1 * 9 + 6 + u];
    Rh2 = 2.0f * LOG2E * rk[2 * 9 + 6 + u];
    Ch = 2.0f * LOG2E * br[6 + u];
    wl = dw[u];  // lane3: wl=0 -> contributes 0 to the quad dot
  }
  float dbv = db[0];

  unsigned uSel = (u < 3u) ? u : 2u;  // lane3 duplicates u=2 (in-bounds)
  const char* p = rec + (size_t)uSel * PLANE_BYTES + (size_t)b * T_SZ * 8u;

  DECL8(A);
  DECL8(B);
  LOAD8(A, p);  // t = 0..15

  float h = 0.0f;
  float o0 = 0, o1 = 0, o2 = 0;

  for (unsigned t0 = 0; t0 < T_SZ; t0 += 32) {
    LOAD8(B, p + (size_t)(t0 + 16) * 8u);           // t0+16 <= 2032: in-bounds
    COMPUTE8(A, t0);
    const char* pA = (t0 + 32 < T_SZ) ? (p + (size_t)(t0 + 32) * 8u) : p;
    LOAD8(A, pA);                                   // last iter: dummy reload
    COMPUTE8(B, t0 + 16);
  }
}

// ---------------------------------------------------------------------------
extern "C" void kernel_launch(void* const* d_in, const int* in_sizes, int n_in,
                              void* d_out, int out_size, void* d_ws,
                              size_t ws_size, hipStream_t stream) {
  const float* x  = (const float*)d_in[0];
  const float* k  = (const float*)d_in[1];
  const float* rk = (const float*)d_in[2];
  const float* bi = (const float*)d_in[3];
  const float* br = (const float*)d_in[4];
  const float* dw = (const float*)d_in[5];
  const float* db = (const float*)d_in[6];
  float* out = (float*)d_out;

  // Pass 1: B*T/2 threads, each does 2 timesteps (one 64B line of x)
  hipLaunchKernelGGL(gru_pass1, dim3((B_SZ * T_SZ / 2) / 256), dim3(256), 0,
                     stream, x, k, bi, br, (unsigned*)d_ws);
  // Pass 2: 4 lanes per batch row, 64-thread blocks spread across CUs
  hipLaunchKernelGGL(gru_scan, dim3((B_SZ * 4) / 64), dim3(64), 0, stream,
                     (const char*)d_ws, rk, br, dw, db, out);
}